// Round 9
// baseline (430.594 us; speedup 1.0000x reference)
//
#include <hip/hip_runtime.h>

typedef unsigned short u16;
typedef __attribute__((ext_vector_type(8))) short vbf16x8;   // 8 bf16 (4 VGPRs)
typedef __attribute__((ext_vector_type(4))) float vf32x4;    // MFMA acc frag

__device__ __forceinline__ float bf2f(u16 u) {
    union { unsigned int i; float f; } v; v.i = ((unsigned int)u) << 16; return v.f;
}
__device__ __forceinline__ u16 f2bf(float f) {
    union { float f; unsigned int i; } v; v.f = f;
    return (u16)((v.i + 0x7fffu + ((v.i >> 16) & 1u)) >> 16);  // RNE
}

struct TPack { const float* src[9]; u16* dst[9]; };

// ============== bucketed CSR build constants ==============
#define NBUK 256
#define NBLK_BIN 256
#define SCAP 24
#define OVFCAP 32768
#define PACK_SH 17   // staged word = (local_key << 17) | val ; val < 2^17

// ---- 9 weight transposes (576 blocks) + ovfn zero (replaces memset) ----
__global__ __launch_bounds__(256) void wtp(TPack p, int* __restrict__ ovfn) {
    int b = blockIdx.x;
    if (b == 0 && threadIdx.x < 2) ovfn[threadIdx.x] = 0;
    int mat = b >> 6;
    const float* s = p.src[mat];
    u16* d = p.dst[mat];
    int i = (b & 63) * 256 + threadIdx.x;
    int k = i >> 7, n = i & 127;
    d[(size_t)n * 128 + k] = f2bf(s[(size_t)k * 128 + n]);
}

// ===== mega2: doc GEMM tiles ∥ edge bin-scatter ∥ author gather ==========
__global__ __launch_bounds__(256) void mega2(
    const float* __restrict__ A1f, const u16* __restrict__ W1T,
    const float* __restrict__ biasd, u16* __restrict__ xdoc, int M, int BD,
    const float* __restrict__ emb, const int* __restrict__ ids,
    u16* __restrict__ xauth, int NA, int gatherB,
    const int* __restrict__ src, const int* __restrict__ dst,
    unsigned* __restrict__ stageD, unsigned* __restrict__ stageA,
    int* __restrict__ cntD, int* __restrict__ cntA,
    uint2* __restrict__ ovfD, uint2* __restrict__ ovfA, int* __restrict__ ovfn,
    int E, int shD, int shA) {
    __shared__ u16 WS[128 * 128];   // 32 KB (GEMM); aliased as lcnt (binning)
    const int tid = threadIdx.x;

    const long b = blockIdx.x;
    const long nB = 2 * NBLK_BIN;
    const long T = (long)BD + nB + gatherB;
    const long gq0 = (b * BD) / T, gq1 = ((b + 1) * BD) / T;

    if (gq1 > gq0) {                       // ---- doc encoder GEMM tile ----
        const int tile = (int)gq0;
        const int lane = tid & 63, wave = tid >> 6;
        const int r15 = lane & 15, kq = lane >> 4;
        const int rowbase = tile * 128 + wave * 32;
        const int m0 = rowbase + r15, m1 = rowbase + 16 + r15;
        const bool v0 = rowbase < M, v1 = rowbase + 16 < M;

        vf32x4 acc0[8], acc1[8];
#pragma unroll
        for (int i = 0; i < 8; ++i) { acc0[i] = (vf32x4)(0.0f); acc1[i] = (vf32x4)(0.0f); }

#pragma unroll
        for (int i = 0; i < 8; ++i) {
            int L = i * 256 + tid;
            int n = L >> 4, bk = L & 15;
            *(uint4*)(WS + ((size_t)n * 16 + (bk ^ (n & 15))) * 8) =
                *(const uint4*)(W1T + (size_t)L * 8);
        }
        __syncthreads();

#pragma unroll
        for (int ks = 0; ks < 4; ++ks) {
            vbf16x8 a0 = (vbf16x8)(short)0, a1 = (vbf16x8)(short)0;
            if (v0) {
                const float* p = A1f + (size_t)m0 * 128 + ks * 32 + kq * 8;
                float4 lo = *(const float4*)p, hi = *(const float4*)(p + 4);
                a0[0] = (short)f2bf(lo.x); a0[1] = (short)f2bf(lo.y);
                a0[2] = (short)f2bf(lo.z); a0[3] = (short)f2bf(lo.w);
                a0[4] = (short)f2bf(hi.x); a0[5] = (short)f2bf(hi.y);
                a0[6] = (short)f2bf(hi.z); a0[7] = (short)f2bf(hi.w);
            }
            if (v1) {
                const float* p = A1f + (size_t)m1 * 128 + ks * 32 + kq * 8;
                float4 lo = *(const float4*)p, hi = *(const float4*)(p + 4);
                a1[0] = (short)f2bf(lo.x); a1[1] = (short)f2bf(lo.y);
                a1[2] = (short)f2bf(lo.z); a1[3] = (short)f2bf(lo.w);
                a1[4] = (short)f2bf(hi.x); a1[5] = (short)f2bf(hi.y);
                a1[6] = (short)f2bf(hi.z); a1[7] = (short)f2bf(hi.w);
            }
#pragma unroll
            for (int nt = 0; nt < 8; ++nt) {
                vbf16x8 bb = *(const vbf16x8*)(
                    WS + ((size_t)(nt * 16 + r15) * 16 + ((ks * 4 + kq) ^ r15)) * 8);
                acc0[nt] = __builtin_amdgcn_mfma_f32_16x16x32_bf16(a0, bb, acc0[nt], 0, 0, 0);
                acc1[nt] = __builtin_amdgcn_mfma_f32_16x16x32_bf16(a1, bb, acc1[nt], 0, 0, 0);
            }
        }

#pragma unroll
        for (int nt = 0; nt < 8; ++nt) {
            const float bv = biasd[nt * 16 + r15];
#pragma unroll
            for (int r = 0; r < 4; ++r) {
                if (v0) xdoc[(size_t)(rowbase + kq * 4 + r) * 128 + nt * 16 + r15] =
                    f2bf(acc0[nt][r] + bv);
                if (v1) xdoc[(size_t)(rowbase + 16 + kq * 4 + r) * 128 + nt * 16 + r15] =
                    f2bf(acc1[nt][r] + bv);
            }
        }
        return;
    }

    const long b2 = b - gq0;               // index among non-GEMM blocks
    const long T2 = T - BD;
    const long bq0 = (b2 * nB) / T2, bq1 = ((b2 + 1) * nB) / T2;

    if (bq1 > bq0) {                       // ---- edge binning ----
        int* lcnt = (int*)WS;              // alias GEMM LDS
        int bb = (int)bq0;
        const bool isD = bb < NBLK_BIN;
        const int blk = isD ? bb : bb - NBLK_BIN;
        const int* key = isD ? src : dst;
        const int* val = isD ? dst : src;
        const int shift = isD ? shD : shA;
        unsigned* stage = isD ? stageD : stageA;
        int* cnt = isD ? cntD : cntA;
        uint2* ovf = isD ? ovfD : ovfA;
        int* on = ovfn + (isD ? 0 : 1);
        const int per = (E + NBLK_BIN - 1) / NBLK_BIN;
        const int beg = blk * per;
        const int end = min(beg + per, E);
        for (int i = tid; i < NBUK; i += 256) lcnt[i] = 0;
        __syncthreads();
        for (int e = beg + tid; e < end; e += 256) {
            int k = key[e], v = val[e];
            int bkt = k >> shift;
            int slot = atomicAdd(&lcnt[bkt], 1);
            if (slot < SCAP) {
                unsigned local = (unsigned)(k - (bkt << shift));
                stage[((size_t)bkt * NBLK_BIN + blk) * SCAP + slot] =
                    (local << PACK_SH) | (unsigned)v;
            } else {                       // rare: spill to overflow list
                int oi = atomicAdd(on, 1);
                if (oi < OVFCAP) ovf[oi] = make_uint2((unsigned)k, (unsigned)v);
            }
        }
        __syncthreads();
        for (int i = tid; i < NBUK; i += 256)
            cnt[(size_t)i * NBLK_BIN + blk] = min(lcnt[i], SCAP);
        return;
    }

    // ---- author row gather ----
    int gid = (int)(b2 - bq0) * 256 + tid;
    if (gid >= NA * 16) return;
    int n = gid >> 4, f = gid & 15;
    int id = ids[n];
    const float* s = emb + (size_t)id * 128 + f * 8;
    float4 lo = *(const float4*)(s);
    float4 hi = *(const float4*)(s + 4);
    u16 o[8] = {f2bf(lo.x), f2bf(lo.y), f2bf(lo.z), f2bf(lo.w),
                f2bf(hi.x), f2bf(hi.y), f2bf(hi.z), f2bf(hi.w)};
    *(uint4*)(xauth + (size_t)n * 128 + f * 8) = *(const uint4*)o;
}

// ---- per-bucket LDS histogram -> per-node counts + per-bucket totals ----
__global__ __launch_bounds__(256) void bucket_count2(
    const unsigned* __restrict__ stageD, const unsigned* __restrict__ stageA,
    const int* __restrict__ cntD, const int* __restrict__ cntA,
    const uint2* __restrict__ ovfD, const uint2* __restrict__ ovfA,
    const int* __restrict__ ovfn,
    int* __restrict__ cnt_d, int* __restrict__ cnt_a, int* __restrict__ btot,
    int ND, int NA, int shD, int shA) {
    __shared__ int hist[1024];
    __shared__ int segc[NBLK_BIN];
    __shared__ int red[256];
    const bool isD = (int)blockIdx.x < NBUK;
    const int b = isD ? (int)blockIdx.x : (int)blockIdx.x - NBUK;
    const int sh = isD ? shD : shA;
    const int N = isD ? ND : NA;
    const int base = b << sh;
    const int range = min(1 << sh, N - base);
    const int tid = threadIdx.x;
    if (range <= 0) { if (tid == 0) btot[blockIdx.x] = 0; return; }
    const unsigned* stage = (isD ? stageD : stageA) + (size_t)b * NBLK_BIN * SCAP;
    const int* scnt = (isD ? cntD : cntA) + (size_t)b * NBLK_BIN;
    const uint2* ovf = isD ? ovfD : ovfA;
    const int nov = min(ovfn[isD ? 0 : 1], OVFCAP);
    int* out = isD ? cnt_d : cnt_a;
    for (int i = tid; i < (1 << sh); i += 256) hist[i] = 0;
    segc[tid] = scnt[tid];
    __syncthreads();
    int my = 0;
    for (int j = tid; j < NBLK_BIN * SCAP; j += 256) {
        int seg = j / SCAP, slot = j - seg * SCAP;
        if (slot < segc[seg]) { atomicAdd(&hist[stage[j] >> PACK_SH], 1); ++my; }
    }
    for (int i = tid; i < nov; i += 256) {
        int k = (int)ovf[i].x;
        if ((k >> sh) == b) { atomicAdd(&hist[k - base], 1); ++my; }
    }
    red[tid] = my;
    __syncthreads();
    for (int s = 128; s > 0; s >>= 1) {
        if (tid < s) red[tid] += red[tid + s];
        __syncthreads();
    }
    if (tid == 0) btot[blockIdx.x] = red[0];
    for (int i = tid; i < range; i += 256) out[base + i] = hist[i];
}

// ---- per-bucket: bucket base (raw btot reduce) + node-level LDS scan ----
__global__ __launch_bounds__(256) void bucket_fill3(
    const unsigned* __restrict__ stageD, const unsigned* __restrict__ stageA,
    const int* __restrict__ cntD, const int* __restrict__ cntA,
    const uint2* __restrict__ ovfD, const uint2* __restrict__ ovfA,
    const int* __restrict__ ovfn,
    const int* __restrict__ cnt_d, const int* __restrict__ cnt_a,
    const int* __restrict__ btot,
    int* __restrict__ offs_d, int* __restrict__ offs_a,
    int* __restrict__ nbr_d, int* __restrict__ nbr_a,
    int ND, int NA, int shD, int shA) {
    __shared__ int lcur[1024];
    __shared__ int segc[NBLK_BIN];
    __shared__ int sh[256];
    __shared__ int carry;
    const bool isD = (int)blockIdx.x < NBUK;
    const int b = isD ? (int)blockIdx.x : (int)blockIdx.x - NBUK;
    const int shft = isD ? shD : shA;
    const int N = isD ? ND : NA;
    const int base = b << shft;
    const int range = min(1 << shft, N - base);
    if (range <= 0) return;
    const unsigned* stage = (isD ? stageD : stageA) + (size_t)b * NBLK_BIN * SCAP;
    const int* scnt = (isD ? cntD : cntA) + (size_t)b * NBLK_BIN;
    const uint2* ovf = isD ? ovfD : ovfA;
    const int nov = min(ovfn[isD ? 0 : 1], OVFCAP);
    const int* cnodes = isD ? cnt_d : cnt_a;
    int* offs = isD ? offs_d : offs_a;
    int* nbr = isD ? nbr_d : nbr_a;
    const int tid = threadIdx.x;
    segc[tid] = scnt[tid];
    {
        const int lo = isD ? 0 : NBUK;
        int acc = 0;
        for (int j = lo + tid; j < (int)blockIdx.x; j += 256) acc += btot[j];
        sh[tid] = acc;
        __syncthreads();
        for (int s = 128; s > 0; s >>= 1) {
            if (tid < s) sh[tid] += sh[tid + s];
            __syncthreads();
        }
        if (tid == 0) carry = sh[0];
        __syncthreads();
    }
    for (int c0 = 0; c0 < range; c0 += 256) {
        int i = c0 + tid;
        int v = (i < range) ? cnodes[base + i] : 0;
        sh[tid] = v;
        __syncthreads();
        for (int off = 1; off < 256; off <<= 1) {
            int t = tid >= off ? sh[tid - off] : 0;
            __syncthreads();
            sh[tid] += t;
            __syncthreads();
        }
        if (i < range) {
            int ex = carry + sh[tid] - v;
            lcur[i] = ex;
            offs[base + i] = ex;
        }
        __syncthreads();
        if (tid == 255) carry += sh[255];
        __syncthreads();
    }
    if (tid == 0) offs[base + range] = carry;  // duplicate of next bucket's base
    __syncthreads();
    for (int j = tid; j < NBLK_BIN * SCAP; j += 256) {
        int seg = j / SCAP, slot = j - seg * SCAP;
        if (slot < segc[seg]) {
            unsigned pk = stage[j];
            int local = pk >> PACK_SH;
            int v = (int)(pk & ((1u << PACK_SH) - 1u));
            nbr[atomicAdd(&lcur[local], 1)] = v;
        }
    }
    for (int i = tid; i < nov; i += 256) {
        int k = (int)ovf[i].x;
        if ((k >> shft) == b)
            nbr[atomicAdd(&lcur[k - base], 1)] = (int)ovf[i].y;
    }
}

// =============== shared bodies: gather-mean block / conv GEMM tile ========
struct AggP { const u16* x; const int* offs; const int* nbr; u16* out; int N; };
struct ConvP {
    const u16* A1b; const u16* W1T;
    const u16* A2b; const u16* W2T;
    const float* bias; u16* out;
    int M; int do_relu; int ntiles;
};

// 16 threads/node, 16 nodes per 256-thread block (blk-local index).
__device__ __forceinline__ void agg_block(const AggP& A, int blk, int tid) {
    int node = blk * 16 + (tid >> 4);
    int f = tid & 15;
    if (node >= A.N) return;
    int lane = tid & 63;
    int gbase = lane & 48;                 // group base lane within wave
    const u16* x = A.x;
    int beg = A.offs[node], end = A.offs[node + 1];
    float acc[8] = {0, 0, 0, 0, 0, 0, 0, 0};

    for (int i = beg; i < end; i += 16) {
        int cnt = end - i; if (cnt > 16) cnt = 16;
        int myn = (i + f < end) ? A.nbr[i + f] : 0;
        int t = 0;
        for (; t + 3 < cnt; t += 4) {      // 4 row-gathers in flight
            int i0 = __shfl(myn, gbase + t);
            int i1 = __shfl(myn, gbase + t + 1);
            int i2 = __shfl(myn, gbase + t + 2);
            int i3 = __shfl(myn, gbase + t + 3);
            uint4 q0 = *(const uint4*)(x + (size_t)i0 * 128 + f * 8);
            uint4 q1 = *(const uint4*)(x + (size_t)i1 * 128 + f * 8);
            uint4 q2 = *(const uint4*)(x + (size_t)i2 * 128 + f * 8);
            uint4 q3 = *(const uint4*)(x + (size_t)i3 * 128 + f * 8);
            acc[0] += bf2f((u16)(q0.x & 0xffff)) + bf2f((u16)(q1.x & 0xffff))
                    + bf2f((u16)(q2.x & 0xffff)) + bf2f((u16)(q3.x & 0xffff));
            acc[1] += bf2f((u16)(q0.x >> 16))    + bf2f((u16)(q1.x >> 16))
                    + bf2f((u16)(q2.x >> 16))    + bf2f((u16)(q3.x >> 16));
            acc[2] += bf2f((u16)(q0.y & 0xffff)) + bf2f((u16)(q1.y & 0xffff))
                    + bf2f((u16)(q2.y & 0xffff)) + bf2f((u16)(q3.y & 0xffff));
            acc[3] += bf2f((u16)(q0.y >> 16))    + bf2f((u16)(q1.y >> 16))
                    + bf2f((u16)(q2.y >> 16))    + bf2f((u16)(q3.y >> 16));
            acc[4] += bf2f((u16)(q0.z & 0xffff)) + bf2f((u16)(q1.z & 0xffff))
                    + bf2f((u16)(q2.z & 0xffff)) + bf2f((u16)(q3.z & 0xffff));
            acc[5] += bf2f((u16)(q0.z >> 16))    + bf2f((u16)(q1.z >> 16))
                    + bf2f((u16)(q2.z >> 16))    + bf2f((u16)(q3.z >> 16));
            acc[6] += bf2f((u16)(q0.w & 0xffff)) + bf2f((u16)(q1.w & 0xffff))
                    + bf2f((u16)(q2.w & 0xffff)) + bf2f((u16)(q3.w & 0xffff));
            acc[7] += bf2f((u16)(q0.w >> 16))    + bf2f((u16)(q1.w >> 16))
                    + bf2f((u16)(q2.w >> 16))    + bf2f((u16)(q3.w >> 16));
        }
        for (; t < cnt; ++t) {
            int i0 = __shfl(myn, gbase + t);
            uint4 q0 = *(const uint4*)(x + (size_t)i0 * 128 + f * 8);
            acc[0] += bf2f((u16)(q0.x & 0xffff));
            acc[1] += bf2f((u16)(q0.x >> 16));
            acc[2] += bf2f((u16)(q0.y & 0xffff));
            acc[3] += bf2f((u16)(q0.y >> 16));
            acc[4] += bf2f((u16)(q0.z & 0xffff));
            acc[5] += bf2f((u16)(q0.z >> 16));
            acc[6] += bf2f((u16)(q0.w & 0xffff));
            acc[7] += bf2f((u16)(q0.w >> 16));
        }
    }
    float inv = 1.0f / fmaxf((float)(end - beg), 1.0f);
    u16 o[8];
#pragma unroll
    for (int j = 0; j < 8; ++j) o[j] = f2bf(acc[j] * inv);
    *(uint4*)(A.out + (size_t)node * 128 + f * 8) = *(const uint4*)o;
}

// 128-row tile, dual-mat (A1@W1 + A2@W2), 32 KB WS restaged per mat.
__device__ __forceinline__ void conv_tile(const ConvP& P, int bx, u16* WS, int tid) {
    const int lane = tid & 63, wave = tid >> 6;
    const int r15 = lane & 15, kq = lane >> 4;
    const int rowbase = bx * 128 + wave * 32;
    const int m0 = rowbase + r15, m1 = rowbase + 16 + r15;
    const bool v0 = rowbase < P.M, v1 = rowbase + 16 < P.M;

    vf32x4 acc0[8], acc1[8];
#pragma unroll
    for (int i = 0; i < 8; ++i) { acc0[i] = (vf32x4)(0.0f); acc1[i] = (vf32x4)(0.0f); }

#pragma unroll
    for (int mat = 0; mat < 2; ++mat) {
        const u16* WT = mat ? P.W2T : P.W1T;
        if (mat) __syncthreads();          // protect WS before overwrite
#pragma unroll
        for (int i = 0; i < 8; ++i) {
            int L = i * 256 + tid;
            int n = L >> 4, bk = L & 15;
            *(uint4*)(WS + ((size_t)n * 16 + (bk ^ (n & 15))) * 8) =
                *(const uint4*)(WT + (size_t)L * 8);
        }
        __syncthreads();

        const u16* Ab = mat ? P.A2b : P.A1b;
#pragma unroll
        for (int ks = 0; ks < 4; ++ks) {
            vbf16x8 a0 = (vbf16x8)(short)0, a1 = (vbf16x8)(short)0;
            if (v0) a0 = *(const vbf16x8*)(Ab + (size_t)m0 * 128 + ks * 32 + kq * 8);
            if (v1) a1 = *(const vbf16x8*)(Ab + (size_t)m1 * 128 + ks * 32 + kq * 8);
#pragma unroll
            for (int nt = 0; nt < 8; ++nt) {
                vbf16x8 b = *(const vbf16x8*)(
                    WS + ((size_t)(nt * 16 + r15) * 16 + ((ks * 4 + kq) ^ r15)) * 8);
                acc0[nt] = __builtin_amdgcn_mfma_f32_16x16x32_bf16(a0, b, acc0[nt], 0, 0, 0);
                acc1[nt] = __builtin_amdgcn_mfma_f32_16x16x32_bf16(a1, b, acc1[nt], 0, 0, 0);
            }
        }
    }

#pragma unroll
    for (int nt = 0; nt < 8; ++nt) {
        const float bv = P.bias[nt * 16 + r15];
#pragma unroll
        for (int r = 0; r < 4; ++r) {
            if (v0) {
                float v = acc0[nt][r] + bv;
                if (P.do_relu) v = fmaxf(v, 0.0f);
                P.out[(size_t)(rowbase + kq * 4 + r) * 128 + nt * 16 + r15] = f2bf(v);
            }
            if (v1) {
                float v = acc1[nt][r] + bv;
                if (P.do_relu) v = fmaxf(v, 0.0f);
                P.out[(size_t)(rowbase + 16 + kq * 4 + r) * 128 + nt * 16 + r15] = f2bf(v);
            }
        }
    }
}

// ---- standalone wrappers ----
__global__ __launch_bounds__(256) void agg_side(AggP A) {
    agg_block(A, blockIdx.x, threadIdx.x);
}
__global__ __launch_bounds__(256) void conv_side(ConvP C) {
    __shared__ u16 WS[128 * 128];
    conv_tile(C, blockIdx.x, WS, threadIdx.x);
}

// ---- fused: conv tiles quota-interleaved among agg gather blocks --------
// The gather (latency-bound, no MFMA) and GEMM (MFMA + LDS, memory-light)
// co-resident on each CU overlap their stalls — the mega2 effect applied
// to the SAGE layer pipeline.
__global__ __launch_bounds__(256) void aggconv(AggP A, int naggB, ConvP C) {
    __shared__ u16 WS[128 * 128];
    const long b = blockIdx.x;
    const long nc = C.ntiles;
    const long T = (long)naggB + nc;
    const long c0 = (b * nc) / T, c1 = ((b + 1) * nc) / T;
    if (c1 > c0) conv_tile(C, (int)c0, WS, threadIdx.x);
    else         agg_block(A, (int)(b - c0), threadIdx.x);
}

// ---------------- edge scorer: pred[e] = dot(od[i0[e]], oa[i1[e]]) --------
__global__ __launch_bounds__(256) void edge_dot(
    const u16* __restrict__ od, const u16* __restrict__ oa,
    const int* __restrict__ i0, const int* __restrict__ i1,
    float* __restrict__ pred, int EL) {
    int gid = blockIdx.x * 256 + threadIdx.x;
    if (gid >= EL * 16) return;
    int e = gid >> 4, f = gid & 15;
    uint4 x = *(const uint4*)(od + (size_t)i0[e] * 128 + f * 8);
    uint4 y = *(const uint4*)(oa + (size_t)i1[e] * 128 + f * 8);
    float s = 0.0f;
    s += bf2f((u16)(x.x & 0xffff)) * bf2f((u16)(y.x & 0xffff));
    s += bf2f((u16)(x.x >> 16))    * bf2f((u16)(y.x >> 16));
    s += bf2f((u16)(x.y & 0xffff)) * bf2f((u16)(y.y & 0xffff));
    s += bf2f((u16)(x.y >> 16))    * bf2f((u16)(y.y >> 16));
    s += bf2f((u16)(x.z & 0xffff)) * bf2f((u16)(y.z & 0xffff));
    s += bf2f((u16)(x.z >> 16))    * bf2f((u16)(y.z >> 16));
    s += bf2f((u16)(x.w & 0xffff)) * bf2f((u16)(y.w & 0xffff));
    s += bf2f((u16)(x.w >> 16))    * bf2f((u16)(y.w >> 16));
    s += __shfl_xor(s, 1);
    s += __shfl_xor(s, 2);
    s += __shfl_xor(s, 4);
    s += __shfl_xor(s, 8);
    if (f == 0) pred[e] = s;
}

extern "C" void kernel_launch(void* const* d_in, const int* in_sizes, int n_in,
                              void* d_out, int out_size, void* d_ws, size_t ws_size,
                              hipStream_t stream) {
    const float* doc_x    = (const float*)d_in[0];
    const int*   auth_id  = (const int*)d_in[1];
    const int*   eidx     = (const int*)d_in[2];
    const int*   elidx    = (const int*)d_in[3];
    const float* W_doc    = (const float*)d_in[4];
    const float* b_doc    = (const float*)d_in[5];
    const float* emb      = (const float*)d_in[6];
    const float* c1_da_Wl = (const float*)d_in[7];
    const float* c1_da_bl = (const float*)d_in[8];
    const float* c1_da_Wr = (const float*)d_in[9];
    const float* c1_ad_Wl = (const float*)d_in[10];
    const float* c1_ad_bl = (const float*)d_in[11];
    const float* c1_ad_Wr = (const float*)d_in[12];
    const float* c2_da_Wl = (const float*)d_in[13];
    const float* c2_da_bl = (const float*)d_in[14];
    const float* c2_da_Wr = (const float*)d_in[15];
    const float* c2_ad_Wl = (const float*)d_in[16];
    const float* c2_ad_bl = (const float*)d_in[17];
    const float* c2_ad_Wr = (const float*)d_in[18];

    const int ND = in_sizes[0] / 128;
    const int NA = in_sizes[1];
    const int E  = in_sizes[2] / 2;
    const int EL = in_sizes[3] / 2;
    const int* e_src = eidx;        // doc endpoints
    const int* e_dst = eidx + E;    // author endpoints
    const int BA = (NA + 127) / 128, BD = (ND + 127) / 128;   // 128-row tiles
    const int gatherB = (NA * 16 + 255) / 256;
    const int aggBA = (NA * 16 + 255) / 256;   // agg blocks, author side
    const int aggBD = (ND * 16 + 255) / 256;   // agg blocks, doc side

    // ---- workspace layout ----
    char* base = (char*)d_ws;
    size_t off = 0;
    auto alloc = [&](size_t bytes) {
        void* p = base + off;
        off = (off + bytes + 255) & ~(size_t)255;
        return p;
    };
    u16*  xdoc  = (u16*)alloc((size_t)ND * 128 * 2);   // later reused as o_d
    u16*  xauth = (u16*)alloc((size_t)NA * 128 * 2);   // later reused as o_a
    u16*  hd    = (u16*)alloc((size_t)ND * 128 * 2);
    u16*  ha    = (u16*)alloc((size_t)NA * 128 * 2);
    // two ND-sized ping-pong agg buffers (liveness-packed; author-side use
    // touches only the first NA rows):
    //   agg1: w5(agg1A) r6(conv1A) / w7(agg2D) r8(conv2D)
    //   agg2: w6(agg1D) r7(conv1D) / w8(agg2A) r9(conv2A)
    u16*  agg1  = (u16*)alloc((size_t)ND * 128 * 2);
    u16*  agg2  = (u16*)alloc((size_t)ND * 128 * 2);
    u16*  wt    = (u16*)alloc((size_t)9 * 128 * 128 * 2);
    int*  cnt   = (int*)alloc((size_t)(ND + NA) * 4);
    int*  offs_d = (int*)alloc((size_t)(ND + 1) * 4);
    int*  offs_a = (int*)alloc((size_t)(NA + 1) * 4);
    int*  nbr_d = (int*)alloc((size_t)E * 4);
    int*  nbr_a = (int*)alloc((size_t)E * 4);
    int*  cntD  = (int*)alloc((size_t)NBUK * NBLK_BIN * 4);
    int*  cntA  = (int*)alloc((size_t)NBUK * NBLK_BIN * 4);
    int*  btot  = (int*)alloc((size_t)2 * NBUK * 4);
    uint2* ovfD = (uint2*)alloc((size_t)OVFCAP * 8);
    uint2* ovfA = (uint2*)alloc((size_t)OVFCAP * 8);
    int*  ovfn  = (int*)alloc(256);
    (void)ws_size; (void)n_in; (void)out_size;
    u16* od = xdoc;   // layer-2 outputs overwrite layer-0 features
    u16* oa = xauth;
    // staging aliases agg1/agg2: stage is dead after phase 4; agg buffers
    // are first written in phases 5/6. 6.29 MB each <= 25.6 MB.
    unsigned* stageD = (unsigned*)agg1;
    unsigned* stageA = (unsigned*)agg2;

    TPack tp;
    const float* srcs[9] = {W_doc, c1_da_Wl, c1_da_Wr, c1_ad_Wl, c1_ad_Wr,
                            c2_da_Wl, c2_da_Wr, c2_ad_Wl, c2_ad_Wr};
    for (int i = 0; i < 9; ++i) { tp.src[i] = srcs[i]; tp.dst[i] = wt + (size_t)i * 16384; }
    const u16 *WTdoc = wt, *WT_c1daL = wt + 16384, *WT_c1daR = wt + 2 * 16384,
              *WT_c1adL = wt + 3 * 16384, *WT_c1adR = wt + 4 * 16384,
              *WT_c2daL = wt + 5 * 16384, *WT_c2daR = wt + 6 * 16384,
              *WT_c2adL = wt + 7 * 16384, *WT_c2adR = wt + 8 * 16384;

    // bucket shifts: smallest s with ((N-1)>>s) < NBUK  (range = 1<<s <= 1024)
    int shD = 0; while (((ND - 1) >> shD) >= NBUK) ++shD;
    int shA = 0; while (((NA - 1) >> shA) >= NBUK) ++shA;

    // ---- 1) weight transposes + ovfn zero ----
    wtp<<<576, 256, 0, stream>>>(tp, ovfn);

    // ---- 2) doc GEMM ∥ edge binning ∥ author gather (interleaved) ----
    mega2<<<BD + 2 * NBLK_BIN + gatherB, 256, 0, stream>>>(
        doc_x, WTdoc, b_doc, xdoc, ND, BD,
        emb, auth_id, xauth, NA, gatherB,
        e_src, e_dst, stageD, stageA, cntD, cntA, ovfD, ovfA, ovfn,
        E, shD, shA);

    // ---- 3) per-node counts + per-bucket totals ----
    bucket_count2<<<2 * NBUK, 256, 0, stream>>>(
        stageD, stageA, cntD, cntA, ovfD, ovfA, ovfn,
        cnt, cnt + ND, btot, ND, NA, shD, shA);

    // ---- 4) bucket base + node-level scan (offs) + nbr fill ----
    bucket_fill3<<<2 * NBUK, 256, 0, stream>>>(
        stageD, stageA, cntD, cntA, ovfD, ovfA, ovfn,
        cnt, cnt + ND, btot, offs_d, offs_a, nbr_d, nbr_a,
        ND, NA, shD, shA);

    // ---- 5) agg1 author side: agg1 = mean_{docs of a} xdoc ----
    {
        AggP A = {xdoc, offs_a, nbr_a, agg1, NA};
        agg_side<<<aggBA, 256, 0, stream>>>(A);
    }

    // ---- 6) agg1 doc side (xauth -> agg2) ∥ conv1 author (agg1 -> ha) ----
    {
        AggP A = {xauth, offs_d, nbr_d, agg2, ND};
        ConvP C = {agg1, WT_c1daL, xauth, WT_c1daR, c1_da_bl, ha, NA, 1, BA};
        aggconv<<<aggBD + BA, 256, 0, stream>>>(A, aggBD, C);
    }

    // ---- 7) agg2 doc side (ha -> agg1) ∥ conv1 doc (agg2 -> hd) ----
    {
        AggP A = {ha, offs_d, nbr_d, agg1, ND};
        ConvP C = {agg2, WT_c1adL, xdoc, WT_c1adR, c1_ad_bl, hd, ND, 1, BD};
        aggconv<<<aggBD + BD, 256, 0, stream>>>(A, aggBD, C);
    }

    // ---- 8) agg2 author side (hd -> agg2) ∥ conv2 doc (agg1 -> od) ----
    {
        AggP A = {hd, offs_a, nbr_a, agg2, NA};
        ConvP C = {agg1, WT_c2adL, hd, WT_c2adR, c2_ad_bl, od, ND, 0, BD};
        aggconv<<<aggBA + BD, 256, 0, stream>>>(A, aggBA, C);
    }

    // ---- 9) conv2 author side (agg2 -> oa) ----
    {
        ConvP C = {agg2, WT_c2daL, ha, WT_c2daR, c2_da_bl, oa, NA, 0, BA};
        conv_side<<<BA, 256, 0, stream>>>(C);
    }

    // ---- 10) edge scorer ----
    edge_dot<<<(EL * 16 + 255) / 256, 256, 0, stream>>>(
        od, oa, elidx, elidx + EL, (float*)d_out, EL);
}